// Round 11
// baseline (144.221 us; speedup 1.0000x reference)
//
#include <hip/hip_runtime.h>
#include <hip/hip_bf16.h>
#include <stdint.h>

#define N_CLOTH     16384
#define N_OBS_VERTS 8192
#define N_OBS_FACES 16384

#define GRID_N  16
#define NCELL   4096
#define GLO     (-2.6f)
#define GH      (5.2f / 16.0f)
#define GINVH   (1.0f / GH)
#define MARGIN  1e-3f      // d^2-space safety margin (>> fp rounding error)

#define NCH  256           // face chunks (16384/64, all full)
#define CHF  64            // faces per chunk
#define VB   16            // verts per k_nn_cull block
#define NR   16            // roles per vert
#define BST  8             // chunks staged per batch

__device__ __forceinline__ unsigned enc_f32(float x) {
    unsigned u = __float_as_uint(x);
    return (u & 0x80000000u) ? ~u : (u | 0x80000000u);
}
__device__ __forceinline__ int expand4(int v) {
    return (v & 1) | ((v & 2) << 2) | ((v & 4) << 4) | ((v & 8) << 6);
}
__device__ __forceinline__ int mcell(float x, float y, float z) {
    int gx = min(max((int)floorf((x - GLO) * GINVH), 0), GRID_N - 1);
    int gy = min(max((int)floorf((y - GLO) * GINVH), 0), GRID_N - 1);
    int gz = min(max((int)floorf((z - GLO) * GINVH), 0), GRID_N - 1);
    return expand4(gx) | (expand4(gy) << 1) | (expand4(gz) << 2);
}

// ---------------------------------------------------------------------------
// K1: faceA (prev center + 0.5||c||^2) + Morton cells + histograms (both sets)
// ---------------------------------------------------------------------------
__global__ __launch_bounds__(256) void k_bin(
    const float* __restrict__ obs_prev, const int* __restrict__ faces,
    const float* __restrict__ cloth_prev,
    float4* __restrict__ faceA, int* __restrict__ cellF, int* __restrict__ cellV,
    int* __restrict__ faceCnt, int* __restrict__ vertCnt)
{
    int i = blockIdx.x * 256 + threadIdx.x;
    int i0 = faces[3 * i + 0];
    int i1 = faces[3 * i + 1];
    int i2 = faces[3 * i + 2];
    float ax = obs_prev[3 * i0 + 0], ay = obs_prev[3 * i0 + 1], az = obs_prev[3 * i0 + 2];
    float bx = obs_prev[3 * i1 + 0], by = obs_prev[3 * i1 + 1], bz = obs_prev[3 * i1 + 2];
    float cx = obs_prev[3 * i2 + 0], cy = obs_prev[3 * i2 + 1], cz = obs_prev[3 * i2 + 2];
    float pcx = (ax + bx + cx) * (1.0f / 3.0f);
    float pcy = (ay + by + cy) * (1.0f / 3.0f);
    float pcz = (az + bz + cz) * (1.0f / 3.0f);
    float b2h = 0.5f * (pcx * pcx + pcy * pcy + pcz * pcz);
    faceA[i] = make_float4(pcx, pcy, pcz, b2h);
    int cf = mcell(pcx, pcy, pcz);
    cellF[i] = cf;
    atomicAdd(&faceCnt[cf], 1);

    float vx = cloth_prev[3 * i + 0];
    float vy = cloth_prev[3 * i + 1];
    float vz = cloth_prev[3 * i + 2];
    int cv = mcell(vx, vy, vz);
    cellV[i] = cv;
    atomicAdd(&vertCnt[cv], 1);
}

// ---------------------------------------------------------------------------
// K2: two exclusive scans over 4096 counts via wave shfl-scan (no barrier loop)
// ---------------------------------------------------------------------------
__global__ __launch_bounds__(1024) void k_scan2(
    const int* __restrict__ faceCnt, const int* __restrict__ vertCnt,
    int* __restrict__ cursorF, int* __restrict__ cursorV)
{
    __shared__ int wsum[16], wbase_s[16];
    int t = threadIdx.x, lane = t & 63, wid = t >> 6;

    // faces
    int v0 = faceCnt[t * 4], v1 = faceCnt[t * 4 + 1];
    int v2 = faceCnt[t * 4 + 2], v3 = faceCnt[t * 4 + 3];
    int s4 = v0 + v1 + v2 + v3;
    int x = s4;
#pragma unroll
    for (int d = 1; d < 64; d <<= 1) { int y = __shfl_up(x, d); if (lane >= d) x += y; }
    if (lane == 63) wsum[wid] = x;
    __syncthreads();
    if (t == 0) { int a = 0; for (int w = 0; w < 16; ++w) { wbase_s[w] = a; a += wsum[w]; } }
    __syncthreads();
    int base = wbase_s[wid] + (x - s4);
    cursorF[t * 4] = base;
    cursorF[t * 4 + 1] = base + v0;
    cursorF[t * 4 + 2] = base + v0 + v1;
    cursorF[t * 4 + 3] = base + v0 + v1 + v2;
    __syncthreads();

    // verts
    v0 = vertCnt[t * 4]; v1 = vertCnt[t * 4 + 1];
    v2 = vertCnt[t * 4 + 2]; v3 = vertCnt[t * 4 + 3];
    s4 = v0 + v1 + v2 + v3;
    x = s4;
#pragma unroll
    for (int d = 1; d < 64; d <<= 1) { int y = __shfl_up(x, d); if (lane >= d) x += y; }
    if (lane == 63) wsum[wid] = x;
    __syncthreads();
    if (t == 0) { int a = 0; for (int w = 0; w < 16; ++w) { wbase_s[w] = a; a += wsum[w]; } }
    __syncthreads();
    base = wbase_s[wid] + (x - s4);
    cursorV[t * 4] = base;
    cursorV[t * 4 + 1] = base + v0;
    cursorV[t * 4 + 2] = base + v0 + v1;
    cursorV[t * 4 + 3] = base + v0 + v1 + v2;
}

// ---------------------------------------------------------------------------
// K3: scatter faces + verts into cell-sorted order (min-over-set result is
// order-independent -> deterministic output despite atomic cursors)
// ---------------------------------------------------------------------------
__global__ __launch_bounds__(256) void k_scatter(
    const float4* __restrict__ faceA, const int* __restrict__ cellF,
    const float* __restrict__ cloth_prev, const int* __restrict__ cellV,
    int* __restrict__ cursorF, int* __restrict__ cursorV,
    float4* __restrict__ faceAS, int* __restrict__ origIdx, float4* __restrict__ vertS)
{
    int i = blockIdx.x * 256 + threadIdx.x;
    int p = atomicAdd(&cursorF[cellF[i]], 1);
    faceAS[p] = faceA[i];
    origIdx[p] = i;
    int q = atomicAdd(&cursorV[cellV[i]], 1);
    vertS[q] = make_float4(cloth_prev[3 * i + 0], cloth_prev[3 * i + 1],
                           cloth_prev[3 * i + 2], __uint_as_float((unsigned)i));
}

// ---------------------------------------------------------------------------
// K4: exact AABB per 64-face chunk
// ---------------------------------------------------------------------------
__global__ __launch_bounds__(64) void k_chunkbb(
    const float4* __restrict__ faceAS,
    float4* __restrict__ bbLo, float4* __restrict__ bbHi)
{
    int c = blockIdx.x, t = threadIdx.x;
    float4 a = faceAS[c * CHF + t];
    float mnx = a.x, mny = a.y, mnz = a.z, mxx = a.x, mxy = a.y, mxz = a.z;
    for (int d = 1; d < 64; d <<= 1) {
        mnx = fminf(mnx, __shfl_xor(mnx, d));
        mny = fminf(mny, __shfl_xor(mny, d));
        mnz = fminf(mnz, __shfl_xor(mnz, d));
        mxx = fmaxf(mxx, __shfl_xor(mxx, d));
        mxy = fmaxf(mxy, __shfl_xor(mxy, d));
        mxz = fmaxf(mxz, __shfl_xor(mxz, d));
    }
    if (t == 0) {
        bbLo[c] = make_float4(mnx, mny, mnz, 0.0f);
        bbHi[c] = make_float4(mxx, mxy, mxz, 0.0f);
    }
}

// ---------------------------------------------------------------------------
// K5: culled NN + fused loss. Block = 16 sorted verts x 16 roles, 1024 blocks.
//   UB  = min_chunk max_vert (far-corner dist^2)   [sound: chunks are full]
//   cull: chunk survives iff gap(blockAABB, chunkAABB)^2 <= UB + MARGIN
//   eval: survivors staged to LDS 8 chunks/batch; dense u64-key min, no
//         per-face branches; one role-combine at the end. Exact jnp.argmin
//   loss: role-0 lanes gather face data, cubic penalty, block sum, atomicAdd.
// ---------------------------------------------------------------------------
__global__ __launch_bounds__(256) void k_nn_cull(
    const float4* __restrict__ vertS,
    const float4* __restrict__ faceAS, const int* __restrict__ origIdx,
    const float4* __restrict__ bbLo, const float4* __restrict__ bbHi,
    const float* __restrict__ cloth_pred,
    const float* __restrict__ obs_pos,
    const int* __restrict__ faces,
    const int* __restrict__ iteration,
    float* __restrict__ out)
{
    const int t = threadIdx.x;
    const int role = t & (NR - 1);
    const int lv = t >> 4;          // local vert 0..15
    const int wv = t >> 6;          // wave 0..3

    __shared__ float4 shv[VB];
    __shared__ float bbw[4][6];
    __shared__ float ubw[4];
    __shared__ unsigned short surv[NCH];
    __shared__ int wcnt[4], wbase[4], nsurvS;
    __shared__ float4 sf[BST * CHF];
    __shared__ int soi[BST * CHF];
    __shared__ float red[256];

    float4 V = vertS[blockIdx.x * VB + lv];
    const float vx = V.x, vy = V.y, vz = V.z;
    if (role == 0) shv[lv] = V;

    // block AABB (wave reduce + cross-wave)
    {
        float mnx = vx, mny = vy, mnz = vz, mxx = vx, mxy = vy, mxz = vz;
        for (int d = 1; d < 64; d <<= 1) {
            mnx = fminf(mnx, __shfl_xor(mnx, d));
            mny = fminf(mny, __shfl_xor(mny, d));
            mnz = fminf(mnz, __shfl_xor(mnz, d));
            mxx = fmaxf(mxx, __shfl_xor(mxx, d));
            mxy = fmaxf(mxy, __shfl_xor(mxy, d));
            mxz = fmaxf(mxz, __shfl_xor(mxz, d));
        }
        if ((t & 63) == 0) {
            bbw[wv][0] = mnx; bbw[wv][1] = mny; bbw[wv][2] = mnz;
            bbw[wv][3] = mxx; bbw[wv][4] = mxy; bbw[wv][5] = mxz;
        }
    }
    __syncthreads();
    const float bmnx = fminf(fminf(bbw[0][0], bbw[1][0]), fminf(bbw[2][0], bbw[3][0]));
    const float bmny = fminf(fminf(bbw[0][1], bbw[1][1]), fminf(bbw[2][1], bbw[3][1]));
    const float bmnz = fminf(fminf(bbw[0][2], bbw[1][2]), fminf(bbw[2][2], bbw[3][2]));
    const float bmxx = fmaxf(fmaxf(bbw[0][3], bbw[1][3]), fmaxf(bbw[2][3], bbw[3][3]));
    const float bmxy = fmaxf(fmaxf(bbw[0][4], bbw[1][4]), fmaxf(bbw[2][4], bbw[3][4]));
    const float bmxz = fmaxf(fmaxf(bbw[0][5], bbw[1][5]), fmaxf(bbw[2][5], bbw[3][5]));

    // UB = min over chunks (thread t = chunk t) of max over 16 verts of
    // far-corner squared distance
    float4 lo = bbLo[t], hi = bbHi[t];
    {
        float mt = 0.0f;
#pragma unroll 4
        for (int v = 0; v < VB; ++v) {
            float4 P = shv[v];
            float fx = fmaxf(P.x - lo.x, hi.x - P.x);
            float fy = fmaxf(P.y - lo.y, hi.y - P.y);
            float fz = fmaxf(P.z - lo.z, hi.z - P.z);
            mt = fmaxf(mt, fx * fx + fy * fy + fz * fz);
        }
        for (int d = 1; d < 64; d <<= 1) mt = fminf(mt, __shfl_xor(mt, d));
        if ((t & 63) == 0) ubw[wv] = mt;
    }
    __syncthreads();
    const float UB = fminf(fminf(ubw[0], ubw[1]), fminf(ubw[2], ubw[3])) + MARGIN;

    // survivor cull (thread t = chunk t), ordered ballot compaction
    bool flag;
    {
        float gx = fmaxf(fmaxf(lo.x - bmxx, bmnx - hi.x), 0.0f);
        float gy = fmaxf(fmaxf(lo.y - bmxy, bmny - hi.y), 0.0f);
        float gz = fmaxf(fmaxf(lo.z - bmxz, bmnz - hi.z), 0.0f);
        flag = (gx * gx + gy * gy + gz * gz) <= UB;
    }
    unsigned long long bm = __ballot(flag);
    if ((t & 63) == 0) wcnt[wv] = __popcll(bm);
    __syncthreads();
    if (t == 0) {
        int s = 0;
        for (int w = 0; w < 4; ++w) { wbase[w] = s; s += wcnt[w]; }
        nsurvS = s;
    }
    __syncthreads();
    if (flag)
        surv[wbase[wv] + __popcll(bm & ((1ull << (t & 63)) - 1ull))] = (unsigned short)t;
    __syncthreads();
    const int nsurv = nsurvS;

    // dense eval over survivor chunks, staged to LDS in batches of 8
    unsigned long long key = 0xFFFFFFFFFFFFFFFFull;
    for (int sb = 0; sb < nsurv; sb += BST) {
        int nf = min(BST, nsurv - sb) * CHF;
        __syncthreads();
        for (int idx = t; idx < nf; idx += 256) {
            int f = (int)surv[sb + (idx >> 6)] * CHF + (idx & 63);
            sf[idx] = faceAS[f];
            soi[idx] = origIdx[f];
        }
        __syncthreads();
        for (int i = role; i < nf; i += NR) {
            float4 b = sf[i];
            float s = fmaf(-vx, b.x, b.w);
            s = fmaf(-vy, b.y, s);
            s = fmaf(-vz, b.z, s);
            unsigned long long k =
                ((unsigned long long)enc_f32(s) << 32) | (unsigned)soi[i];
            key = (k < key) ? k : key;
        }
    }
    // combine across the 16 roles (contiguous lanes within a wave)
    {
        unsigned long long o = __shfl_xor(key, 1); key = (o < key) ? o : key;
        o = __shfl_xor(key, 2); key = (o < key) ? o : key;
        o = __shfl_xor(key, 4); key = (o < key) ? o : key;
        o = __shfl_xor(key, 8); key = (o < key) ? o : key;
    }

    // fused loss (one lane per vertex)
    float val = 0.0f;
    if (role == 0) {
        int idx = (int)(unsigned)(key & 0xFFFFFFFFull);
        int n = (int)__float_as_uint(V.w);
        int i0 = faces[3 * idx + 0];
        int i1 = faces[3 * idx + 1];
        int i2 = faces[3 * idx + 2];
        float ux = obs_pos[3 * i0 + 0], uy = obs_pos[3 * i0 + 1], uz = obs_pos[3 * i0 + 2];
        float wx1 = obs_pos[3 * i1 + 0], wy1 = obs_pos[3 * i1 + 1], wz1 = obs_pos[3 * i1 + 2];
        float wx2 = obs_pos[3 * i2 + 0], wy2 = obs_pos[3 * i2 + 1], wz2 = obs_pos[3 * i2 + 2];

        float fpx = (ux + wx1 + wx2) * (1.0f / 3.0f);
        float fpy = (uy + wy1 + wy2) * (1.0f / 3.0f);
        float fpz = (uz + wz1 + wz2) * (1.0f / 3.0f);

        float e1x = wx1 - ux, e1y = wy1 - uy, e1z = wz1 - uz;
        float e2x = wx2 - ux, e2y = wy2 - uy, e2z = wz2 - uz;
        float nx = e1y * e2z - e1z * e2y;
        float ny = e1z * e2x - e1x * e2z;
        float nz = e1x * e2y - e1y * e2x;
        float nrm = sqrtf(nx * nx + ny * ny + nz * nz);
        float inv = 1.0f / fmaxf(nrm, 1e-12f);

        float px = cloth_pred[3 * n + 0];
        float py = cloth_pred[3 * n + 1];
        float pz = cloth_pred[3 * n + 2];
        float d = (px - fpx) * nx * inv + (py - fpy) * ny * inv + (pz - fpz) * nz * inv;
        float tt = fmaxf(1e-3f - d, 0.0f);
        val = tt * tt * tt;
    }
    red[t] = val;
    __syncthreads();
    for (int s = 128; s > 0; s >>= 1) {
        if (t < s) red[t] += red[t + s];
        __syncthreads();
    }
    if (t == 0) {
        int it = iteration[0];
        float itf = fmaxf((float)(it - 50000), 0.0f);
        float prog = fminf(itf * (1.0f / 100000.0f), 1.0f);
        float w = 1.0f + (5000.0f - 1.0f) * prog;
        atomicAdd(out, red[0] * w);
    }
}

extern "C" void kernel_launch(void* const* d_in, const int* in_sizes, int n_in,
                              void* d_out, int out_size, void* d_ws, size_t ws_size,
                              hipStream_t stream) {
    const float* obs_pos    = (const float*)d_in[0];
    const float* obs_prev   = (const float*)d_in[1];
    const int*   faces      = (const int*)d_in[2];
    const float* cloth_prev = (const float*)d_in[3];
    const float* cloth_pred = (const float*)d_in[4];
    const int*   iteration  = (const int*)d_in[5];
    float* out = (float*)d_out;

    char* ws = (char*)d_ws;
    float4* faceA     = (float4*)(ws + 0);         // 262144
    float4* faceAS    = (float4*)(ws + 262144);    // 262144
    int*    origIdx   = (int*)(ws + 524288);       // 65536
    int*    cellF     = (int*)(ws + 589824);       // 65536
    int*    cellV     = (int*)(ws + 655360);       // 65536
    float4* vertS     = (float4*)(ws + 720896);    // 262144
    int*    faceCnt   = (int*)(ws + 983040);       // 16384  \ zeroed together
    int*    vertCnt   = (int*)(ws + 999424);       // 16384  /
    int*    cursorF   = (int*)(ws + 1015808);      // 16384
    int*    cursorV   = (int*)(ws + 1032192);      // 16384
    float4* bbLo      = (float4*)(ws + 1048576);   // 4096
    float4* bbHi      = (float4*)(ws + 1052672);   // 4096

    hipMemsetAsync(ws + 983040, 0, 32768, stream);
    hipMemsetAsync(out, 0, sizeof(float), stream);

    k_bin<<<64, 256, 0, stream>>>(
        obs_prev, faces, cloth_prev, faceA, cellF, cellV, faceCnt, vertCnt);
    k_scan2<<<1, 1024, 0, stream>>>(faceCnt, vertCnt, cursorF, cursorV);
    k_scatter<<<64, 256, 0, stream>>>(
        faceA, cellF, cloth_prev, cellV, cursorF, cursorV, faceAS, origIdx, vertS);
    k_chunkbb<<<NCH, 64, 0, stream>>>(faceAS, bbLo, bbHi);
    k_nn_cull<<<N_CLOTH / VB, 256, 0, stream>>>(
        vertS, faceAS, origIdx, bbLo, bbHi, cloth_pred, obs_pos, faces, iteration, out);
}

// Round 12
// 43.543 us; speedup vs baseline: 3.3122x; 3.3122x over previous
//
#include <hip/hip_runtime.h>
#include <hip/hip_bf16.h>
#include <stdint.h>

#define N_CLOTH     16384
#define N_OBS_VERTS 8192
#define N_OBS_FACES 16384

#define CHUNK 128                        // faces per chunk (LDS tile = 2KB)
#define NC    (N_OBS_FACES / CHUNK)      // 128 chunks
#define VPT   8                          // vertices per thread
#define TB    256                        // threads per block
#define VBLK  (N_CLOTH / (TB * VPT))     // 8 vertex-blocks -> grid 8x128 = 1024 blocks

// ---------------------------------------------------------------------------
// K0: prev-face centers -> faceA[f] = (cx, cy, cz, 0.5*||c||^2); also zeroes
// the output accumulator (replaces a memset graph node).
// Single source of truth: k_nn stages faceA; k_reduce re-reads it bit-identically.
// ---------------------------------------------------------------------------
__global__ __launch_bounds__(256) void k_faces(
    const float* __restrict__ obs_prev, const int* __restrict__ faces,
    float4* __restrict__ faceA, float* __restrict__ out)
{
    int f = blockIdx.x * blockDim.x + threadIdx.x;
    if (f == 0) out[0] = 0.0f;
    if (f >= N_OBS_FACES) return;
    int i0 = faces[3 * f + 0];
    int i1 = faces[3 * f + 1];
    int i2 = faces[3 * f + 2];
    float ax = obs_prev[3 * i0 + 0], ay = obs_prev[3 * i0 + 1], az = obs_prev[3 * i0 + 2];
    float bx = obs_prev[3 * i1 + 0], by = obs_prev[3 * i1 + 1], bz = obs_prev[3 * i1 + 2];
    float cx = obs_prev[3 * i2 + 0], cy = obs_prev[3 * i2 + 1], cz = obs_prev[3 * i2 + 2];
    float pcx = (ax + bx + cx) * (1.0f / 3.0f);
    float pcy = (ay + by + cy) * (1.0f / 3.0f);
    float pcz = (az + bz + cz) * (1.0f / 3.0f);
    float b2h = 0.5f * (pcx * pcx + pcy * pcy + pcz * pcz);
    faceA[f] = make_float4(pcx, pcy, pcz, b2h);
}

// ---------------------------------------------------------------------------
// K1: value-only NN scan (identical to R7's 43.6 us version). 14 VALU / 4
// pairs: 12 fma + v_min3(s0,s1,s2) + v_min3(m,s3,best).
// chunkMin[c][n] = min_{f in chunk c} s(n,f),  s = 0.5||b||^2 - a.b
// (monotone in d2 per vertex; min3/fminf return one of their inputs, so the
//  min is bit-equal to some s -- k_reduce relies on that for index recovery)
// ---------------------------------------------------------------------------
__global__ __launch_bounds__(TB) void k_nn(
    const float* __restrict__ cloth_prev,
    const float4* __restrict__ faceA,
    float* __restrict__ chunkMin)          // [NC][N_CLOTH]
{
    __shared__ float4 tile[CHUNK];
    const int t = threadIdx.x;
    const int bv = blockIdx.x;      // vertex block 0..VBLK-1
    const int c  = blockIdx.y;      // face chunk   0..NC-1
    const int fbase = c * CHUNK;

    if (t < CHUNK) tile[t] = faceA[fbase + t];

    float vx[VPT], vy[VPT], vz[VPT], best[VPT];
#pragma unroll
    for (int j = 0; j < VPT; ++j) {
        int n = bv * (TB * VPT) + j * TB + t;
        vx[j] = cloth_prev[3 * n + 0];
        vy[j] = cloth_prev[3 * n + 1];
        vz[j] = cloth_prev[3 * n + 2];
        best[j] = 3.4e38f;
    }
    __syncthreads();

#pragma unroll 2
    for (int gi = 0; gi < CHUNK / 4; ++gi) {
        float4 b0 = tile[4 * gi + 0];
        float4 b1 = tile[4 * gi + 1];
        float4 b2 = tile[4 * gi + 2];
        float4 b3 = tile[4 * gi + 3];
#pragma unroll
        for (int j = 0; j < VPT; ++j) {
            float s0 = fmaf(-vx[j], b0.x, b0.w);
            s0 = fmaf(-vy[j], b0.y, s0);
            s0 = fmaf(-vz[j], b0.z, s0);
            float s1 = fmaf(-vx[j], b1.x, b1.w);
            s1 = fmaf(-vy[j], b1.y, s1);
            s1 = fmaf(-vz[j], b1.z, s1);
            float s2 = fmaf(-vx[j], b2.x, b2.w);
            s2 = fmaf(-vy[j], b2.y, s2);
            s2 = fmaf(-vz[j], b2.z, s2);
            float s3 = fmaf(-vx[j], b3.x, b3.w);
            s3 = fmaf(-vy[j], b3.y, s3);
            s3 = fmaf(-vz[j], b3.z, s3);
            float m = fminf(fminf(s0, s1), s2);       // v_min3_f32
            best[j] = fminf(fminf(m, s3), best[j]);   // v_min3_f32
        }
    }

#pragma unroll
    for (int j = 0; j < VPT; ++j) {
        int n = bv * (TB * VPT) + j * TB + t;
        chunkMin[(size_t)c * N_CLOTH + n] = best[j];
    }
}

// ---------------------------------------------------------------------------
// K2: 4 threads per vertex (grid 256 blocks x 256 thr).
// phase 1: value-only f32 min over this role's 32 chunks (held in registers,
//          full unroll), cross-role min via shfl; earliest chunk recovered by
//          register equality-rescan (ascending-from-high select -> lowest c;
//          roles own contiguous chunk ranges so cross-role min-index is the
//          global earliest chunk == jnp.argmin tie-break order).
// phase 2: rescan the 128 faces of the winning chunk (32/role) with the
//          bit-identical fmaf chain; descending equality select -> lowest q.
// leader does the loss math; block sum; weight; atomicAdd -> out.
// ---------------------------------------------------------------------------
__global__ __launch_bounds__(256) void k_reduce(
    const float* __restrict__ cloth_prev,
    const float* __restrict__ cloth_pred,
    const float4* __restrict__ faceA,
    const float* __restrict__ chunkMin,
    const float* __restrict__ obs_pos,
    const int* __restrict__ faces,
    const int* __restrict__ iteration,
    float* __restrict__ out)
{
    const int t = threadIdx.x;
    const int r = t & 3;                       // role within vertex
    const int n = blockIdx.x * 64 + (t >> 2);  // vertex id

    // ---- phase 1: f32 min over this role's 32 chunks (registers) ----
    float vals[NC / 4];
    float m = 3.4e38f;
#pragma unroll
    for (int i = 0; i < NC / 4; ++i) {
        vals[i] = chunkMin[(size_t)(r * (NC / 4) + i) * N_CLOTH + n];
        m = fminf(vals[i], m);
    }
    m = fminf(m, __shfl_xor(m, 1));
    m = fminf(m, __shfl_xor(m, 2));          // global min value (bit-exact)

    int cbr = 0x7FFFFFFF;
#pragma unroll
    for (int i = NC / 4 - 1; i >= 0; --i)
        cbr = (vals[i] == m) ? r * (NC / 4) + i : cbr;   // lowest i in role
    {
        int o = __shfl_xor(cbr, 1); cbr = min(cbr, o);
        o = __shfl_xor(cbr, 2); cbr = min(cbr, o);       // earliest chunk
    }
    const int cb = cbr;

    // ---- phase 2: lowest face in chunk cb with s == m (bit-exact) ----
    const float vx = cloth_prev[3 * n + 0];
    const float vy = cloth_prev[3 * n + 1];
    const float vz = cloth_prev[3 * n + 2];
    const int fbase = cb * CHUNK;
    int match = 0x7FFFFFFF;
#pragma unroll 8
    for (int qq = CHUNK / 4 - 1; qq >= 0; --qq) {
        int q = r * (CHUNK / 4) + qq;
        float4 b = faceA[fbase + q];
        float s = fmaf(-vx, b.x, b.w);
        s = fmaf(-vy, b.y, s);
        s = fmaf(-vz, b.z, s);
        match = (s == m) ? q : match;          // descending -> lowest q wins
    }
    {
        int o = __shfl_xor(match, 1); match = min(match, o);
        o = __shfl_xor(match, 2); match = min(match, o);
    }
    const int idx = fbase + match;

    // ---- leader computes the loss term ----
    float val = 0.0f;
    if (r == 0) {
        int i0 = faces[3 * idx + 0];
        int i1 = faces[3 * idx + 1];
        int i2 = faces[3 * idx + 2];
        float ux = obs_pos[3 * i0 + 0], uy = obs_pos[3 * i0 + 1], uz = obs_pos[3 * i0 + 2];
        float wx1 = obs_pos[3 * i1 + 0], wy1 = obs_pos[3 * i1 + 1], wz1 = obs_pos[3 * i1 + 2];
        float wx2 = obs_pos[3 * i2 + 0], wy2 = obs_pos[3 * i2 + 1], wz2 = obs_pos[3 * i2 + 2];

        float fpx = (ux + wx1 + wx2) * (1.0f / 3.0f);
        float fpy = (uy + wy1 + wy2) * (1.0f / 3.0f);
        float fpz = (uz + wz1 + wz2) * (1.0f / 3.0f);

        float e1x = wx1 - ux, e1y = wy1 - uy, e1z = wz1 - uz;
        float e2x = wx2 - ux, e2y = wy2 - uy, e2z = wz2 - uz;
        float nx = e1y * e2z - e1z * e2y;
        float ny = e1z * e2x - e1x * e2z;
        float nz = e1x * e2y - e1y * e2x;
        float nrm = sqrtf(nx * nx + ny * ny + nz * nz);
        float inv = 1.0f / fmaxf(nrm, 1e-12f);

        float px = cloth_pred[3 * n + 0];
        float py = cloth_pred[3 * n + 1];
        float pz = cloth_pred[3 * n + 2];
        float d = (px - fpx) * nx * inv + (py - fpy) * ny * inv + (pz - fpz) * nz * inv;
        float tt = fmaxf(1e-3f - d, 0.0f);
        val = tt * tt * tt;
    }

    __shared__ float red[256];
    red[t] = val;
    __syncthreads();
    for (int s = 128; s > 0; s >>= 1) {
        if (t < s) red[t] += red[t + s];
        __syncthreads();
    }
    if (t == 0) {
        int it = iteration[0];
        float itf = fmaxf((float)(it - 50000), 0.0f);
        float prog = fminf(itf * (1.0f / 100000.0f), 1.0f);
        float w = 1.0f + (5000.0f - 1.0f) * prog;
        atomicAdd(out, red[0] * w);
    }
}

extern "C" void kernel_launch(void* const* d_in, const int* in_sizes, int n_in,
                              void* d_out, int out_size, void* d_ws, size_t ws_size,
                              hipStream_t stream) {
    const float* obs_pos    = (const float*)d_in[0];
    const float* obs_prev   = (const float*)d_in[1];
    const int*   faces      = (const int*)d_in[2];
    const float* cloth_prev = (const float*)d_in[3];
    const float* cloth_pred = (const float*)d_in[4];
    const int*   iteration  = (const int*)d_in[5];
    float* out = (float*)d_out;

    char* ws = (char*)d_ws;
    float4* faceA    = (float4*)(ws);                 // 256 KB
    float*  chunkMin = (float*)(ws + 262144);         // 8.4 MB [NC][N]

    k_faces<<<N_OBS_FACES / 256, 256, 0, stream>>>(obs_prev, faces, faceA, out);
    k_nn<<<dim3(VBLK, NC), TB, 0, stream>>>(cloth_prev, faceA, chunkMin);
    k_reduce<<<N_CLOTH * 4 / 256, 256, 0, stream>>>(
        cloth_prev, cloth_pred, faceA, chunkMin, obs_pos, faces, iteration, out);
}

// Round 13
// 42.893 us; speedup vs baseline: 3.3624x; 1.0152x over previous
//
#include <hip/hip_runtime.h>
#include <hip/hip_bf16.h>
#include <stdint.h>

#define N_CLOTH     16384
#define N_OBS_VERTS 8192
#define N_OBS_FACES 16384

#define CHUNK 128                        // faces per chunk (LDS tile = 2KB SoA)
#define NC    (N_OBS_FACES / CHUNK)      // 128 chunks
#define VPT   8                          // vertices per thread
#define TB    256                        // threads per block
#define VBLK  (N_CLOTH / (TB * VPT))     // 8 vertex-blocks -> grid 8x128 = 1024 blocks

typedef float v2f __attribute__((ext_vector_type(2)));

// 1 VOP3P instruction: d = a*b + c per component (IEEE fp32 fma each)
__device__ __forceinline__ v2f pk_fma(v2f a, v2f b, v2f c) {
    v2f d;
    asm("v_pk_fma_f32 %0, %1, %2, %3" : "=v"(d) : "v"(a), "v"(b), "v"(c));
    return d;
}

// ---------------------------------------------------------------------------
// K0: prev-face centers -> faceA[f] = (cx, cy, cz, 0.5*||c||^2); also zeroes
// the output accumulator. k_nn stages faceA; k_reduce re-reads bit-identically.
// ---------------------------------------------------------------------------
__global__ __launch_bounds__(256) void k_faces(
    const float* __restrict__ obs_prev, const int* __restrict__ faces,
    float4* __restrict__ faceA, float* __restrict__ out)
{
    int f = blockIdx.x * blockDim.x + threadIdx.x;
    if (f == 0) out[0] = 0.0f;
    if (f >= N_OBS_FACES) return;
    int i0 = faces[3 * f + 0];
    int i1 = faces[3 * f + 1];
    int i2 = faces[3 * f + 2];
    float ax = obs_prev[3 * i0 + 0], ay = obs_prev[3 * i0 + 1], az = obs_prev[3 * i0 + 2];
    float bx = obs_prev[3 * i1 + 0], by = obs_prev[3 * i1 + 1], bz = obs_prev[3 * i1 + 2];
    float cx = obs_prev[3 * i2 + 0], cy = obs_prev[3 * i2 + 1], cz = obs_prev[3 * i2 + 2];
    float pcx = (ax + bx + cx) * (1.0f / 3.0f);
    float pcy = (ay + by + cy) * (1.0f / 3.0f);
    float pcz = (az + bz + cz) * (1.0f / 3.0f);
    float b2h = 0.5f * (pcx * pcx + pcy * pcy + pcz * pcz);
    faceA[f] = make_float4(pcx, pcy, pcz, b2h);
}

// ---------------------------------------------------------------------------
// K1: value-only NN scan, packed-fp32 inner loop. Per 4-face group / vertex:
//   6 v_pk_fma_f32 + 2 v_min3_f32 = 8 VALU instrs (2.0 per pair).
// LDS tile is SoA (x[128], y[128], z[128], w[128]); group reads are four
// wave-uniform b128 broadcasts. s-chain per component is the same IEEE fma
// sequence as k_reduce's scalar recompute -> bit-identical minima.
// chunkMin[c][n] = min_{f in chunk c} s(n,f),  s = 0.5||b||^2 - a.b
// ---------------------------------------------------------------------------
__global__ __launch_bounds__(TB) void k_nn(
    const float* __restrict__ cloth_prev,
    const float4* __restrict__ faceA,
    float* __restrict__ chunkMin)          // [NC][N_CLOTH]
{
    __shared__ float4 tX[CHUNK / 4], tY[CHUNK / 4], tZ[CHUNK / 4], tW[CHUNK / 4];
    const int t = threadIdx.x;
    const int bv = blockIdx.x;      // vertex block 0..VBLK-1
    const int c  = blockIdx.y;      // face chunk   0..NC-1
    const int fbase = c * CHUNK;

    if (t < CHUNK) {
        float4 b = faceA[fbase + t];
        ((float*)tX)[t] = b.x;
        ((float*)tY)[t] = b.y;
        ((float*)tZ)[t] = b.z;
        ((float*)tW)[t] = b.w;
    }

    v2f nx2[VPT], ny2[VPT], nz2[VPT];
    float best[VPT];
#pragma unroll
    for (int j = 0; j < VPT; ++j) {
        int n = bv * (TB * VPT) + j * TB + t;
        float vx = cloth_prev[3 * n + 0];
        float vy = cloth_prev[3 * n + 1];
        float vz = cloth_prev[3 * n + 2];
        nx2[j] = (v2f){-vx, -vx};
        ny2[j] = (v2f){-vy, -vy};
        nz2[j] = (v2f){-vz, -vz};
        best[j] = 3.4e38f;
    }
    __syncthreads();

#pragma unroll 2
    for (int gi = 0; gi < CHUNK / 4; ++gi) {
        float4 X = tX[gi], Y = tY[gi], Z = tZ[gi], W = tW[gi];
        v2f Xa = {X.x, X.y}, Xb = {X.z, X.w};
        v2f Ya = {Y.x, Y.y}, Yb = {Y.z, Y.w};
        v2f Za = {Z.x, Z.y}, Zb = {Z.z, Z.w};
        v2f Wa = {W.x, W.y}, Wb = {W.z, W.w};
#pragma unroll
        for (int j = 0; j < VPT; ++j) {
            v2f s01 = pk_fma(nx2[j], Xa, Wa);
            s01 = pk_fma(ny2[j], Ya, s01);
            s01 = pk_fma(nz2[j], Za, s01);
            v2f s23 = pk_fma(nx2[j], Xb, Wb);
            s23 = pk_fma(ny2[j], Yb, s23);
            s23 = pk_fma(nz2[j], Zb, s23);
            float m = fminf(fminf(s01.x, s01.y), s23.x);   // v_min3_f32
            best[j] = fminf(fminf(m, s23.y), best[j]);     // v_min3_f32
        }
    }

#pragma unroll
    for (int j = 0; j < VPT; ++j) {
        int n = bv * (TB * VPT) + j * TB + t;
        chunkMin[(size_t)c * N_CLOTH + n] = best[j];
    }
}

// ---------------------------------------------------------------------------
// K2: 4 threads per vertex (grid 256 blocks x 256 thr).
// phase 1: f32 min over this role's 32 chunks (registers, full unroll),
//          cross-role min via shfl; earliest chunk by register equality-rescan.
// phase 2: rescan the 128 faces of the winning chunk (32/role) with the
//          bit-identical scalar fmaf chain; descending select -> lowest q.
// leader does the loss math; block sum; weight; atomicAdd -> out.
// ---------------------------------------------------------------------------
__global__ __launch_bounds__(256) void k_reduce(
    const float* __restrict__ cloth_prev,
    const float* __restrict__ cloth_pred,
    const float4* __restrict__ faceA,
    const float* __restrict__ chunkMin,
    const float* __restrict__ obs_pos,
    const int* __restrict__ faces,
    const int* __restrict__ iteration,
    float* __restrict__ out)
{
    const int t = threadIdx.x;
    const int r = t & 3;                       // role within vertex
    const int n = blockIdx.x * 64 + (t >> 2);  // vertex id

    // ---- phase 1: f32 min over this role's 32 chunks (registers) ----
    float vals[NC / 4];
    float m = 3.4e38f;
#pragma unroll
    for (int i = 0; i < NC / 4; ++i) {
        vals[i] = chunkMin[(size_t)(r * (NC / 4) + i) * N_CLOTH + n];
        m = fminf(vals[i], m);
    }
    m = fminf(m, __shfl_xor(m, 1));
    m = fminf(m, __shfl_xor(m, 2));          // global min value (bit-exact)

    int cbr = 0x7FFFFFFF;
#pragma unroll
    for (int i = NC / 4 - 1; i >= 0; --i)
        cbr = (vals[i] == m) ? r * (NC / 4) + i : cbr;   // lowest i in role
    {
        int o = __shfl_xor(cbr, 1); cbr = min(cbr, o);
        o = __shfl_xor(cbr, 2); cbr = min(cbr, o);       // earliest chunk
    }
    const int cb = cbr;

    // ---- phase 2: lowest face in chunk cb with s == m (bit-exact) ----
    const float vx = cloth_prev[3 * n + 0];
    const float vy = cloth_prev[3 * n + 1];
    const float vz = cloth_prev[3 * n + 2];
    const int fbase = cb * CHUNK;
    int match = 0x7FFFFFFF;
#pragma unroll 8
    for (int qq = CHUNK / 4 - 1; qq >= 0; --qq) {
        int q = r * (CHUNK / 4) + qq;
        float4 b = faceA[fbase + q];
        float s = fmaf(-vx, b.x, b.w);
        s = fmaf(-vy, b.y, s);
        s = fmaf(-vz, b.z, s);
        match = (s == m) ? q : match;          // descending -> lowest q wins
    }
    {
        int o = __shfl_xor(match, 1); match = min(match, o);
        o = __shfl_xor(match, 2); match = min(match, o);
    }
    const int idx = fbase + match;

    // ---- leader computes the loss term ----
    float val = 0.0f;
    if (r == 0) {
        int i0 = faces[3 * idx + 0];
        int i1 = faces[3 * idx + 1];
        int i2 = faces[3 * idx + 2];
        float ux = obs_pos[3 * i0 + 0], uy = obs_pos[3 * i0 + 1], uz = obs_pos[3 * i0 + 2];
        float wx1 = obs_pos[3 * i1 + 0], wy1 = obs_pos[3 * i1 + 1], wz1 = obs_pos[3 * i1 + 2];
        float wx2 = obs_pos[3 * i2 + 0], wy2 = obs_pos[3 * i2 + 1], wz2 = obs_pos[3 * i2 + 2];

        float fpx = (ux + wx1 + wx2) * (1.0f / 3.0f);
        float fpy = (uy + wy1 + wy2) * (1.0f / 3.0f);
        float fpz = (uz + wz1 + wz2) * (1.0f / 3.0f);

        float e1x = wx1 - ux, e1y = wy1 - uy, e1z = wz1 - uz;
        float e2x = wx2 - ux, e2y = wy2 - uy, e2z = wz2 - uz;
        float nx = e1y * e2z - e1z * e2y;
        float ny = e1z * e2x - e1x * e2z;
        float nz = e1x * e2y - e1y * e2x;
        float nrm = sqrtf(nx * nx + ny * ny + nz * nz);
        float inv = 1.0f / fmaxf(nrm, 1e-12f);

        float px = cloth_pred[3 * n + 0];
        float py = cloth_pred[3 * n + 1];
        float pz = cloth_pred[3 * n + 2];
        float d = (px - fpx) * nx * inv + (py - fpy) * ny * inv + (pz - fpz) * nz * inv;
        float tt = fmaxf(1e-3f - d, 0.0f);
        val = tt * tt * tt;
    }

    __shared__ float red[256];
    red[t] = val;
    __syncthreads();
    for (int s = 128; s > 0; s >>= 1) {
        if (t < s) red[t] += red[t + s];
        __syncthreads();
    }
    if (t == 0) {
        int it = iteration[0];
        float itf = fmaxf((float)(it - 50000), 0.0f);
        float prog = fminf(itf * (1.0f / 100000.0f), 1.0f);
        float w = 1.0f + (5000.0f - 1.0f) * prog;
        atomicAdd(out, red[0] * w);
    }
}

extern "C" void kernel_launch(void* const* d_in, const int* in_sizes, int n_in,
                              void* d_out, int out_size, void* d_ws, size_t ws_size,
                              hipStream_t stream) {
    const float* obs_pos    = (const float*)d_in[0];
    const float* obs_prev   = (const float*)d_in[1];
    const int*   faces      = (const int*)d_in[2];
    const float* cloth_prev = (const float*)d_in[3];
    const float* cloth_pred = (const float*)d_in[4];
    const int*   iteration  = (const int*)d_in[5];
    float* out = (float*)d_out;

    char* ws = (char*)d_ws;
    float4* faceA    = (float4*)(ws);                 // 256 KB
    float*  chunkMin = (float*)(ws + 262144);         // 8.4 MB [NC][N]

    k_faces<<<N_OBS_FACES / 256, 256, 0, stream>>>(obs_prev, faces, faceA, out);
    k_nn<<<dim3(VBLK, NC), TB, 0, stream>>>(cloth_prev, faceA, chunkMin);
    k_reduce<<<N_CLOTH * 4 / 256, 256, 0, stream>>>(
        cloth_prev, cloth_pred, faceA, chunkMin, obs_pos, faces, iteration, out);
}